// Round 6
// baseline (9735.544 us; speedup 1.0000x reference)
//
#include <hip/hip_runtime.h>
#include <hip/hip_bf16.h>
#include <hip/hip_fp16.h>

__device__ __forceinline__ float siluf(float x) {
    return x / (1.0f + __expf(-x));
}

// ---------------- init: species + s = W_embed[z], v = 0, deg = 0 ----------------
__global__ void k_init(const float* __restrict__ attrs, const float* __restrict__ Wemb,
                       int* __restrict__ species, int* __restrict__ deg,
                       float* __restrict__ s, float* __restrict__ v, int N) {
    int lane = threadIdx.x;
    int n0 = blockIdx.x * 64;
    for (int r = 0; r < 64; r++) {
        int n = n0 + r;
        if (n >= N) break;
        float a = (lane < 10) ? attrs[n * 10 + lane] : 0.0f;
        unsigned long long m = __ballot(a > 0.5f);
        int z = __ffsll(m) - 1;
        if (lane == 0) { species[n] = z; deg[n] = 0; }
        s[n * 64 + lane] = Wemb[z * 64 + lane];
        v[n * 192 + lane] = 0.0f;
        v[n * 192 + 64 + lane] = 0.0f;
        v[n * 192 + 128 + lane] = 0.0f;
    }
}

// ---------------- counting sort by receiver ----------------
__global__ void k_hist(const int* __restrict__ ei, int* __restrict__ deg, int E) {
    int e = blockIdx.x * 256 + threadIdx.x;
    if (e < E) atomicAdd(&deg[ei[E + e]], 1);
}

__global__ void k_scan(const int* __restrict__ deg, int* __restrict__ rowptr,
                       int* __restrict__ cursor, int N) {
    __shared__ int part[1024];
    int t = threadIdx.x;
    int chunk = (N + 1023) / 1024;
    int lo = t * chunk, hi = min(lo + chunk, N);
    int sum = 0;
    for (int i = lo; i < hi; i++) sum += deg[i];
    part[t] = sum;
    __syncthreads();
    for (int off = 1; off < 1024; off <<= 1) {
        int add = (t >= off) ? part[t - off] : 0;
        __syncthreads();
        part[t] += add;
        __syncthreads();
    }
    int run = (t > 0) ? part[t - 1] : 0;
    for (int i = lo; i < hi; i++) { rowptr[i] = run; cursor[i] = run; run += deg[i]; }
    if (t == 1023) rowptr[N] = part[1023];
}

__global__ void k_perm(const int* __restrict__ ei, int* __restrict__ cursor,
                       int* __restrict__ perm, int E) {
    int e = blockIdx.x * 256 + threadIdx.x;
    if (e < E) {
        int r = ei[E + e];
        int pos = atomicAdd(&cursor[r], 1);
        perm[pos] = e;
    }
}

// ---------------- geometry + radial basis on SORTED edge order ----------------
__global__ void k_geom(const int* __restrict__ ei, const int* __restrict__ perm,
                       const float* __restrict__ pos, const float* __restrict__ shifts,
                       float4* __restrict__ geo, float* __restrict__ efT,
                       int* __restrict__ snd_s, int E) {
    int j = blockIdx.x * 64 + threadIdx.x;
    if (j >= E) return;
    int e = perm[j];
    int snd = ei[e], rcv = ei[E + e];
    float dx = pos[rcv * 3 + 0] - pos[snd * 3 + 0] + shifts[e * 3 + 0];
    float dy = pos[rcv * 3 + 1] - pos[snd * 3 + 1] + shifts[e * 3 + 1];
    float dz = pos[rcv * 3 + 2] - pos[snd * 3 + 2] + shifts[e * 3 + 2];
    float r = sqrtf(dx * dx + dy * dy + dz * dz);
    float rin = 1.0f / (r + 1e-9f);
    const float SQ3 = 1.7320508075688772f;
    geo[j] = make_float4(SQ3 * dx * rin, SQ3 * dy * rin, SQ3 * dz * rin, 0.0f);
    snd_s[j] = snd;
    float u = r * 0.2f;
    float env = 0.0f;
    if (u < 1.0f) {
        float u2 = u * u;
        float u6 = u2 * u2 * u2;
        env = 1.0f - 28.0f * u6 + 48.0f * u6 * u - 21.0f * u6 * u2;
    }
    const float PIF = 3.14159265358979f;
    float x = PIF * u;
    float sp = __sinf(x), cp = __cosf(x);
    float coef = 0.6324555320336759f * rin * env;
    float sm1 = 0.0f, scur = sp, twoc = 2.0f * cp;
    #pragma unroll
    for (int k = 0; k < 8; k++) {
        efT[k * (size_t)E + j] = coef * scur;
        float nxt = twoc * scur - sm1;
        sm1 = scur; scur = nxt;
    }
}

// ---------------- generic 64-node tile GEMV ----------------
__device__ __forceinline__ void tile_mv64(const float* __restrict__ in, int istride,
                                          const float* __restrict__ W,
                                          float* __restrict__ outp, int ostride,
                                          float* __restrict__ packf, int comp,
                                          int n0, int nv, float* lds, int lane) {
    for (int r = 0; r < nv; r++) lds[r * 65 + lane] = in[(size_t)(n0 + r) * istride + lane];
    __syncthreads();
    float acc[64];
    #pragma unroll
    for (int d = 0; d < 64; d++) acc[d] = 0.0f;
    for (int c = 0; c < 64; c++) {
        float x = lds[lane * 65 + c];
        const float* wr = W + c * 64;
        #pragma unroll
        for (int d = 0; d < 64; d++) acc[d] = fmaf(x, wr[d], acc[d]);
    }
    __syncthreads();
    #pragma unroll
    for (int d = 0; d < 64; d++) lds[lane * 65 + d] = acc[d];
    __syncthreads();
    for (int r = 0; r < nv; r++) {
        float val = lds[r * 65 + lane];
        if (outp) outp[(size_t)(n0 + r) * ostride + lane] = val;
        if (packf) packf[(((size_t)(n0 + r)) * 64 + lane) * 4 + comp] = val;
    }
    __syncthreads();
}

// 4 GEMVs: s @ Ws and v[x] @ Wv; optionally into packed float4 layout
__global__ void k_4mv(const float* __restrict__ ins, const float* __restrict__ inv,
                      const float* __restrict__ Ws, const float* __restrict__ Wv,
                      float* __restrict__ outs, float* __restrict__ outv,
                      float* __restrict__ packf, int N) {
    __shared__ float lds[64 * 65];
    int lane = threadIdx.x;
    int n0 = blockIdx.x * 64;
    int nv = min(64, N - n0);
    tile_mv64(ins, 64, Ws, outs, 64, packf, 0, n0, nv, lds, lane);
    for (int x = 0; x < 3; x++)
        tile_mv64(inv + x * 64, 192, Wv, outv ? outv + x * 64 : nullptr, 192,
                  packf, 1 + x, n0, nv, lds, lane);
}

// ---- message kernel v3: streamed h1 chunks, h2 regs -> packed half2 regs, no LDS ----
// Peak live VGPRs ~90-110; __launch_bounds__(256,3) gives ~168 budget -> no spill.
__global__ __launch_bounds__(256, 3)
void k_msg(const int* __restrict__ rowptr, int na, int nb,
           const float* __restrict__ efT, const float4* __restrict__ geo,
           const int* __restrict__ snd_s, const float4* __restrict__ pack,
           const float* __restrict__ RW1, const float* __restrict__ RW2,
           const float* __restrict__ RW3, float2* __restrict__ msg,
           int cap, int E) {
    const int tid = threadIdx.x;
    const int Jlo = rowptr[na], Jhi = rowptr[nb];
    const int j = Jlo + blockIdx.x * 256 + tid;
    if (j >= Jhi) return;
    const int idx = j - Jlo;
    const bool live = (idx < cap);

    float ef[8];
    #pragma unroll
    for (int k = 0; k < 8; k++) ef[k] = efT[k * (size_t)E + j];

    // h2 accumulators; h1 streamed through t[16] chunks (never 64 h1 live at once)
    float h2[64];
    #pragma unroll
    for (int d = 0; d < 64; d++) h2[d] = 0.0f;
    #pragma unroll
    for (int hc = 0; hc < 4; hc++) {
        float t[16];
        #pragma unroll
        for (int q = 0; q < 16; q++) t[q] = 0.0f;
        #pragma unroll
        for (int k = 0; k < 8; k++) {
            float x = ef[k];
            const float* wr = RW1 + k * 64 + hc * 16;
            #pragma unroll
            for (int q = 0; q < 16; q++) t[q] = fmaf(x, wr[q], t[q]);
        }
        #pragma unroll
        for (int q = 0; q < 16; q++) t[q] = siluf(t[q]);
        #pragma unroll
        for (int q = 0; q < 16; q++) {
            float x = t[q];
            const float* wr = RW2 + (hc * 16 + q) * 64;
            #pragma unroll
            for (int d = 0; d < 64; d++) h2[d] = fmaf(x, wr[d], h2[d]);
        }
    }
    // silu + pack h2 into 32 half2 regs (statically indexed below); h2 dies here
    __half2 h2p[32];
    #pragma unroll
    for (int p = 0; p < 32; p++)
        h2p[p] = __floats2half2_rn(siluf(h2[2 * p]), siluf(h2[2 * p + 1]));

    const int snd = snd_s[j];
    const float4 g = geo[j];
    const float4* __restrict__ prow = pack + (size_t)snd * 64;
    float2* __restrict__ mrow = msg + (size_t)idx * 64;

    const float inv32 = 1.0f / 32.0f;
    const float is3 = 0.5773502691896258f;   // 1/sqrt(3)
    const float is2 = 0.7071067811865476f;   // 1/sqrt(2)

    for (int cc = 0; cc < 8; cc++) {
        float w[40];
        #pragma unroll
        for (int q = 0; q < 40; q++) w[q] = 0.0f;
        #pragma unroll
        for (int c2 = 0; c2 < 32; c2++) {
            float2 f = __half22float2(h2p[c2]);
            const float* wr0 = RW3 + (2 * c2) * 320 + cc * 8;
            const float* wr1 = wr0 + 320;
            #pragma unroll
            for (int q = 0; q < 5; q++) {
                #pragma unroll
                for (int jj = 0; jj < 8; jj++) {
                    w[q * 8 + jj] = fmaf(f.x, wr0[q * 64 + jj], w[q * 8 + jj]);
                    w[q * 8 + jj] = fmaf(f.y, wr1[q * 64 + jj], w[q * 8 + jj]);
                }
            }
        }
        #pragma unroll
        for (int jj = 0; jj < 8; jj++) {
            const int c = cc * 8 + jj;
            float4 pv = prow[c];  // (s_up, v0, v1, v2) of sender
            float w00  = w[jj];
            float w110 = w[8 + jj];
            float w011 = w[16 + jj];
            float w101 = w[24 + jj];
            float w111 = w[32 + jj];
            float dvy = pv.y * g.x + pv.z * g.y + pv.w * g.z;
            float m0 = (w00 * pv.x + w110 * dvy * is3) * inv32;
            float cxv = pv.z * g.z - pv.w * g.y;
            float cyv = pv.w * g.x - pv.y * g.z;
            float czv = pv.y * g.y - pv.z * g.x;
            float m1x = (w011 * pv.x * g.x + w101 * pv.y + w111 * cxv * is2) * inv32;
            float m1y = (w011 * pv.x * g.y + w101 * pv.z + w111 * cyv * is2) * inv32;
            float m1z = (w011 * pv.x * g.z + w101 * pv.w + w111 * czv * is2) * inv32;
            union { __half2 h; float f; } ua, ub;
            ua.h = __floats2half2_rn(m0, m1x);
            ub.h = __floats2half2_rn(m1y, m1z);
            if (live) mrow[c] = make_float2(ua.f, ub.f);
        }
    }
}

// ---------------- CSR aggregation: wave per node, lane = channel ----------------
__global__ void k_agg(const float2* __restrict__ msg, const int* __restrict__ rowptr,
                      float* __restrict__ agg0, float* __restrict__ agg1,
                      int na, int nb, int cap) {
    int n = na + blockIdx.x * 4 + (threadIdx.x >> 6);
    int lane = threadIdx.x & 63;
    if (n >= nb) return;
    int Jlo = rowptr[na];
    int j0 = rowptr[n], j1 = rowptr[n + 1];
    float a0 = 0.0f, a1 = 0.0f, a2 = 0.0f, a3 = 0.0f;
    for (int j = j0; j < j1; j++) {
        int idx = j - Jlo;
        if (idx >= cap) break;
        float2 m = msg[(size_t)idx * 64 + lane];
        union { float f; __half2 h; } ua, ub;
        ua.f = m.x; ub.f = m.y;
        float2 fa = __half22float2(ua.h);
        float2 fb = __half22float2(ub.h);
        a0 += fa.x; a1 += fa.y; a2 += fb.x; a3 += fb.y;
    }
    size_t nbase = (size_t)n;
    agg0[nbase * 64 + lane] = a0;
    agg1[nbase * 192 + lane] = a1;
    agg1[nbase * 192 + 64 + lane] = a2;
    agg1[nbase * 192 + 128 + lane] = a3;
}

// ---------------- species-dependent skip connections (wave = node) ----------------
__global__ void k_sc(const float* __restrict__ s, const float* __restrict__ v,
                     const int* __restrict__ species, const float* __restrict__ Wsc_s,
                     const float* __restrict__ Wsc_v, float* __restrict__ sc_s,
                     float* __restrict__ sc_v, int N) {
    int n = blockIdx.x;
    if (n >= N) return;
    int lane = threadIdx.x;
    int z = species[n];
    const float* Ws = Wsc_s + (size_t)z * 4096;
    const float* Wv = Wsc_v + (size_t)z * 4096;
    size_t nb = (size_t)n;
    float sreg = s[nb * 64 + lane];
    float acc = 0.0f;
    for (int c = 0; c < 64; c++)
        acc = fmaf(__shfl(sreg, c), Ws[c * 64 + lane], acc);
    sc_s[nb * 64 + lane] = acc;
    for (int x = 0; x < 3; x++) {
        float vreg = v[nb * 192 + x * 64 + lane];
        float av = 0.0f;
        for (int c = 0; c < 64; c++)
            av = fmaf(__shfl(vreg, c), Wv[c * 64 + lane], av);
        sc_v[nb * 192 + x * 64 + lane] = av;
    }
}

// ---------------- prod_s -> new s + output slot ----------------
__global__ void k_prod_s(const float* __restrict__ ms, const float* __restrict__ mv,
                         const float* __restrict__ P0l, const int* __restrict__ species,
                         const float* __restrict__ Wp, const float* __restrict__ sc_s,
                         float* __restrict__ s, float* __restrict__ out,
                         int N, int layer, int L) {
    __shared__ float lds[64 * 65];
    int lane = threadIdx.x;
    int n0 = blockIdx.x * 64;
    int nv = min(64, N - n0);
    for (int r = 0; r < nv; r++) {
        size_t n = n0 + r;
        int z = species[n];
        float msv = ms[n * 64 + lane];
        float a = mv[n * 192 + lane];
        float b = mv[n * 192 + 64 + lane];
        float cq = mv[n * 192 + 128 + lane];
        float mq = a * a + b * b + cq * cq;
        const float* p = P0l + ((size_t)z * 64 + lane) * 3;
        lds[r * 65 + lane] = p[0] * msv + p[1] * msv * msv + p[2] * mq;
    }
    __syncthreads();
    float acc[64];
    #pragma unroll
    for (int d = 0; d < 64; d++) acc[d] = 0.0f;
    for (int c = 0; c < 64; c++) {
        float x = lds[lane * 65 + c];
        const float* wr = Wp + c * 64;
        #pragma unroll
        for (int d = 0; d < 64; d++) acc[d] = fmaf(x, wr[d], acc[d]);
    }
    __syncthreads();
    #pragma unroll
    for (int d = 0; d < 64; d++) lds[lane * 65 + d] = acc[d];
    __syncthreads();
    for (int r = 0; r < nv; r++) {
        size_t n = n0 + r;
        float val = lds[r * 65 + lane] + sc_s[n * 64 + lane];
        s[n * 64 + lane] = val;
        out[n * (size_t)(L * 64) + layer * 64 + lane] = val;
    }
}

// ---------------- prod_v -> new v ----------------
__global__ void k_prod_v(const float* __restrict__ ms, const float* __restrict__ mv,
                         const float* __restrict__ P1l, const int* __restrict__ species,
                         const float* __restrict__ Wp, const float* __restrict__ sc_v,
                         float* __restrict__ v, int N) {
    __shared__ float lds[64 * 65];
    int lane = threadIdx.x;
    int n0 = blockIdx.x * 64;
    int nv = min(64, N - n0);
    for (int x = 0; x < 3; x++) {
        for (int r = 0; r < nv; r++) {
            size_t n = n0 + r;
            int z = species[n];
            float msv = ms[n * 64 + lane];
            float mvv = mv[n * 192 + x * 64 + lane];
            const float* q = P1l + ((size_t)z * 64 + lane) * 2;
            lds[r * 65 + lane] = (q[0] + q[1] * msv) * mvv;
        }
        __syncthreads();
        float acc[64];
        #pragma unroll
        for (int d = 0; d < 64; d++) acc[d] = 0.0f;
        for (int c = 0; c < 64; c++) {
            float xx = lds[lane * 65 + c];
            const float* wr = Wp + c * 64;
            #pragma unroll
            for (int d = 0; d < 64; d++) acc[d] = fmaf(xx, wr[d], acc[d]);
        }
        __syncthreads();
        #pragma unroll
        for (int d = 0; d < 64; d++) lds[lane * 65 + d] = acc[d];
        __syncthreads();
        for (int r = 0; r < nv; r++) {
            size_t n = n0 + r;
            v[n * 192 + x * 64 + lane] = lds[r * 65 + lane] + sc_v[n * 192 + x * 64 + lane];
        }
        __syncthreads();
    }
}

extern "C" void kernel_launch(void* const* d_in, const int* in_sizes, int n_in,
                              void* d_out, int out_size, void* d_ws, size_t ws_size,
                              hipStream_t stream) {
    const float* node_attrs = (const float*)d_in[0];
    const float* atom_pos   = (const float*)d_in[1];
    const float* shifts     = (const float*)d_in[2];
    const float* W_embed    = (const float*)d_in[3];
    const float* Wup_s      = (const float*)d_in[4];
    const float* Wup_v      = (const float*)d_in[5];
    const float* RW1        = (const float*)d_in[6];
    const float* RW2        = (const float*)d_in[7];
    const float* RW3        = (const float*)d_in[8];
    const float* Wout_s     = (const float*)d_in[9];
    const float* Wout_v     = (const float*)d_in[10];
    const float* Wsc_s      = (const float*)d_in[11];
    const float* Wsc_v      = (const float*)d_in[12];
    const float* P0         = (const float*)d_in[13];
    const float* P1         = (const float*)d_in[14];
    const float* Wprod_s    = (const float*)d_in[15];
    const float* Wprod_v    = (const float*)d_in[16];
    const int*   ei         = (const int*)d_in[17];

    const int N = in_sizes[0] / 10;
    const int E = in_sizes[17] / 2;
    const int L = in_sizes[4] / 4096;
    float* out = (float*)d_out;

    char* wsb = (char*)d_ws;
    size_t off = 0;
    auto alloci = [&](size_t n) {
        int* p = (int*)(wsb + off);
        off = (off + n * 4 + 255) / 256 * 256;
        return p;
    };
    auto allocf = [&](size_t n) {
        float* p = (float*)(wsb + off);
        off = (off + n * 4 + 255) / 256 * 256;
        return p;
    };
    int* species = alloci(N);
    int* deg     = alloci(N);
    int* rowptr  = alloci(N + 1);
    int* cursor  = alloci(N);
    int* perm    = alloci(E);
    int* snd_s   = alloci(E);
    float* s     = allocf((size_t)N * 64);
    float* v     = allocf((size_t)N * 192);
    float* agg0  = allocf((size_t)N * 64);   // reused in-place as ms
    float* agg1  = allocf((size_t)N * 192);  // reused in-place as mv
    float* geo   = allocf((size_t)E * 4);
    float* efT   = allocf((size_t)E * 8);
    float* pack  = allocf((size_t)N * 256);
    // sc_s/sc_v alias pack (lifetimes disjoint within a layer)
    float* sc_s  = pack;
    float* sc_v  = pack + (size_t)N * 64;

    // pick NCHUNK at runtime from ws_size (constant per session -> graph-safe)
    int NCHUNK = 16;
    int cap = 0;
    {
        const int cands[8] = {1, 2, 3, 4, 6, 8, 12, 16};
        for (int ci = 0; ci < 8; ci++) {
            int c = cands[ci];
            int thiscap = (c == 1) ? E : (E / c) * 5 / 4 + 256;
            size_t need = off + (size_t)thiscap * 512;  // 128 floats * 4B per edge
            if (need <= ws_size) { NCHUNK = c; cap = thiscap; break; }
        }
        if (cap == 0) { NCHUNK = 16; cap = (E / 16) * 5 / 4 + 256; }
    }
    float* msg = allocf((size_t)cap * 128);   // fp16 half4 = float2 per (edge,ch)
    (void)n_in; (void)out_size;

    const int NT = (N + 63) / 64;
    const int ET = (E + 63) / 64;
    const int EB = (E + 255) / 256;
    const int MT = (cap + 255) / 256;          // k_msg grid per chunk

    k_init<<<NT, 64, 0, stream>>>(node_attrs, W_embed, species, deg, s, v, N);
    k_hist<<<EB, 256, 0, stream>>>(ei, deg, E);
    k_scan<<<1, 1024, 0, stream>>>(deg, rowptr, cursor, N);
    k_perm<<<EB, 256, 0, stream>>>(ei, cursor, perm, E);
    k_geom<<<ET, 64, 0, stream>>>(ei, perm, atom_pos, shifts,
                                  (float4*)geo, efT, snd_s, E);

    int nbound[17];
    for (int k = 0; k <= NCHUNK; k++) nbound[k] = (int)((long long)N * k / NCHUNK);

    for (int i = 0; i < L; i++) {
        k_4mv<<<NT, 64, 0, stream>>>(s, v, Wup_s + (size_t)i * 4096, Wup_v + (size_t)i * 4096,
                                     nullptr, nullptr, pack, N);
        for (int k = 0; k < NCHUNK; k++) {
            int na = nbound[k], nb = nbound[k + 1];
            k_msg<<<MT, 256, 0, stream>>>(rowptr, na, nb, efT, (const float4*)geo, snd_s,
                                          (const float4*)pack,
                                          RW1 + (size_t)i * 512, RW2 + (size_t)i * 4096,
                                          RW3 + (size_t)i * 20480, (float2*)msg, cap, E);
            int cnt = nb - na;
            k_agg<<<(cnt + 3) / 4, 256, 0, stream>>>((const float2*)msg, rowptr,
                                                     agg0, agg1, na, nb, cap);
        }
        k_sc<<<N, 64, 0, stream>>>(s, v, species, Wsc_s + (size_t)i * 40960,
                                   Wsc_v + (size_t)i * 40960, sc_s, sc_v, N);
        k_4mv<<<NT, 64, 0, stream>>>(agg0, agg1, Wout_s + (size_t)i * 4096,
                                     Wout_v + (size_t)i * 4096, agg0, agg1, nullptr, N);
        k_prod_s<<<NT, 64, 0, stream>>>(agg0, agg1, P0 + (size_t)i * 1920, species,
                                        Wprod_s + (size_t)i * 4096, sc_s, s, out, N, i, L);
        k_prod_v<<<NT, 64, 0, stream>>>(agg0, agg1, P1 + (size_t)i * 1280, species,
                                        Wprod_v + (size_t)i * 4096, sc_v, v, N);
    }
}

// Round 7
// 1137.569 us; speedup vs baseline: 8.5582x; 8.5582x over previous
//
#include <hip/hip_runtime.h>
#include <hip/hip_bf16.h>
#include <hip/hip_fp16.h>

typedef _Float16 half8 __attribute__((ext_vector_type(8)));
typedef float floatx4 __attribute__((ext_vector_type(4)));

__device__ __forceinline__ float siluf(float x) {
    return x / (1.0f + __expf(-x));
}

// ---------------- init: species + s = W_embed[z], v = 0, deg = 0 ----------------
__global__ void k_init(const float* __restrict__ attrs, const float* __restrict__ Wemb,
                       int* __restrict__ species, int* __restrict__ deg,
                       float* __restrict__ s, float* __restrict__ v, int N) {
    int lane = threadIdx.x;
    int n0 = blockIdx.x * 64;
    for (int r = 0; r < 64; r++) {
        int n = n0 + r;
        if (n >= N) break;
        float a = (lane < 10) ? attrs[n * 10 + lane] : 0.0f;
        unsigned long long m = __ballot(a > 0.5f);
        int z = __ffsll(m) - 1;
        if (lane == 0) { species[n] = z; deg[n] = 0; }
        s[n * 64 + lane] = Wemb[z * 64 + lane];
        v[n * 192 + lane] = 0.0f;
        v[n * 192 + 64 + lane] = 0.0f;
        v[n * 192 + 128 + lane] = 0.0f;
    }
}

// ---------------- counting sort by receiver ----------------
__global__ void k_hist(const int* __restrict__ ei, int* __restrict__ deg, int E) {
    int e = blockIdx.x * 256 + threadIdx.x;
    if (e < E) atomicAdd(&deg[ei[E + e]], 1);
}

__global__ void k_scan(const int* __restrict__ deg, int* __restrict__ rowptr,
                       int* __restrict__ cursor, int N) {
    __shared__ int part[1024];
    int t = threadIdx.x;
    int chunk = (N + 1023) / 1024;
    int lo = t * chunk, hi = min(lo + chunk, N);
    int sum = 0;
    for (int i = lo; i < hi; i++) sum += deg[i];
    part[t] = sum;
    __syncthreads();
    for (int off = 1; off < 1024; off <<= 1) {
        int add = (t >= off) ? part[t - off] : 0;
        __syncthreads();
        part[t] += add;
        __syncthreads();
    }
    int run = (t > 0) ? part[t - 1] : 0;
    for (int i = lo; i < hi; i++) { rowptr[i] = run; cursor[i] = run; run += deg[i]; }
    if (t == 1023) rowptr[N] = part[1023];
}

__global__ void k_perm(const int* __restrict__ ei, int* __restrict__ cursor,
                       int* __restrict__ perm, int E) {
    int e = blockIdx.x * 256 + threadIdx.x;
    if (e < E) {
        int r = ei[E + e];
        int pos = atomicAdd(&cursor[r], 1);
        perm[pos] = e;
    }
}

// ---------------- geometry + radial basis on SORTED edge order ----------------
__global__ void k_geom(const int* __restrict__ ei, const int* __restrict__ perm,
                       const float* __restrict__ pos, const float* __restrict__ shifts,
                       float4* __restrict__ geo, float* __restrict__ efT,
                       int* __restrict__ snd_s, int E) {
    int j = blockIdx.x * 64 + threadIdx.x;
    if (j >= E) return;
    int e = perm[j];
    int snd = ei[e], rcv = ei[E + e];
    float dx = pos[rcv * 3 + 0] - pos[snd * 3 + 0] + shifts[e * 3 + 0];
    float dy = pos[rcv * 3 + 1] - pos[snd * 3 + 1] + shifts[e * 3 + 1];
    float dz = pos[rcv * 3 + 2] - pos[snd * 3 + 2] + shifts[e * 3 + 2];
    float r = sqrtf(dx * dx + dy * dy + dz * dz);
    float rin = 1.0f / (r + 1e-9f);
    const float SQ3 = 1.7320508075688772f;
    geo[j] = make_float4(SQ3 * dx * rin, SQ3 * dy * rin, SQ3 * dz * rin, 0.0f);
    snd_s[j] = snd;
    float u = r * 0.2f;
    float env = 0.0f;
    if (u < 1.0f) {
        float u2 = u * u;
        float u6 = u2 * u2 * u2;
        env = 1.0f - 28.0f * u6 + 48.0f * u6 * u - 21.0f * u6 * u2;
    }
    const float PIF = 3.14159265358979f;
    float x = PIF * u;
    float sp = __sinf(x), cp = __cosf(x);
    float coef = 0.6324555320336759f * rin * env;
    float sm1 = 0.0f, scur = sp, twoc = 2.0f * cp;
    #pragma unroll
    for (int k = 0; k < 8; k++) {
        efT[k * (size_t)E + j] = coef * scur;
        float nxt = twoc * scur - sm1;
        sm1 = scur; scur = nxt;
    }
}

// -------- weight prep: RW1/RW2/RW3 -> fp16 B-fragment layout for 16x16x32 MFMA ------
// B-frag: lane holds B[k = (lane>>4)*8 + j + kt*32][n = nt*16 + (lane&15)], j=0..7.
__global__ void k_wprep(const float* __restrict__ RW1, const float* __restrict__ RW2,
                        const float* __restrict__ RW3, _Float16* __restrict__ B1f,
                        _Float16* __restrict__ B2f, _Float16* __restrict__ B3f) {
    int lane = threadIdx.x;
    int t = blockIdx.x;
    int layer = t / 52;
    int tt = t % 52;
    int quad = lane >> 4, colx = lane & 15;
    if (tt < 4) {
        int nt = tt;
        const float* W = RW1 + (size_t)layer * 512;
        _Float16* dst = B1f + (size_t)layer * 2048 + ((size_t)nt * 64 + lane) * 8;
        #pragma unroll
        for (int j = 0; j < 8; j++) {
            int k = quad * 8 + j, n = nt * 16 + colx;
            dst[j] = (k < 8) ? (_Float16)W[k * 64 + n] : (_Float16)0.0f;
        }
    } else if (tt < 12) {
        int u = tt - 4;
        int kt = u >> 2, nt = u & 3;
        const float* W = RW2 + (size_t)layer * 4096;
        _Float16* dst = B2f + (size_t)layer * 4096 + (((size_t)kt * 4 + nt) * 64 + lane) * 8;
        #pragma unroll
        for (int j = 0; j < 8; j++) {
            int k = kt * 32 + quad * 8 + j, n = nt * 16 + colx;
            dst[j] = (_Float16)W[k * 64 + n];
        }
    } else {
        int u = tt - 12;
        int kt = u / 20, nt = u % 20;
        const float* W = RW3 + (size_t)layer * 20480;
        _Float16* dst = B3f + (size_t)layer * 20480 + (((size_t)kt * 20 + nt) * 64 + lane) * 8;
        #pragma unroll
        for (int j = 0; j < 8; j++) {
            int k = kt * 32 + quad * 8 + j, n = nt * 16 + colx;
            dst[j] = (_Float16)W[k * 320 + n];
        }
    }
}

// ---------------- generic 64-node tile GEMV ----------------
__device__ __forceinline__ void tile_mv64(const float* __restrict__ in, int istride,
                                          const float* __restrict__ W,
                                          float* __restrict__ outp, int ostride,
                                          float* __restrict__ packf, int comp,
                                          int n0, int nv, float* lds, int lane) {
    for (int r = 0; r < nv; r++) lds[r * 65 + lane] = in[(size_t)(n0 + r) * istride + lane];
    __syncthreads();
    float acc[64];
    #pragma unroll
    for (int d = 0; d < 64; d++) acc[d] = 0.0f;
    for (int c = 0; c < 64; c++) {
        float x = lds[lane * 65 + c];
        const float* wr = W + c * 64;
        #pragma unroll
        for (int d = 0; d < 64; d++) acc[d] = fmaf(x, wr[d], acc[d]);
    }
    __syncthreads();
    #pragma unroll
    for (int d = 0; d < 64; d++) lds[lane * 65 + d] = acc[d];
    __syncthreads();
    for (int r = 0; r < nv; r++) {
        float val = lds[r * 65 + lane];
        if (outp) outp[(size_t)(n0 + r) * ostride + lane] = val;
        if (packf) packf[(((size_t)(n0 + r)) * 64 + lane) * 4 + comp] = val;
    }
    __syncthreads();
}

// 4 GEMVs: s @ Ws and v[x] @ Wv; optionally into packed float4 layout
__global__ void k_4mv(const float* __restrict__ ins, const float* __restrict__ inv,
                      const float* __restrict__ Ws, const float* __restrict__ Wv,
                      float* __restrict__ outs, float* __restrict__ outv,
                      float* __restrict__ packf, int N) {
    __shared__ float lds[64 * 65];
    int lane = threadIdx.x;
    int n0 = blockIdx.x * 64;
    int nv = min(64, N - n0);
    tile_mv64(ins, 64, Ws, outs, 64, packf, 0, n0, nv, lds, lane);
    for (int x = 0; x < 3; x++)
        tile_mv64(inv + x * 64, 192, Wv, outv ? outv + x * 64 : nullptr, 192,
                  packf, 1 + x, n0, nv, lds, lane);
}

// ---- message kernel v4: MFMA edge-MLP. wave = 16 edges; h1/h2 via per-wave LDS ----
// MFMA layouts (HW-verified): C/D: row m = (lane>>4)*4+reg, col n = lane&15.
//                             A: A[m=lane&15][k=(lane>>4)*8+j].
//                             B: B[k=(lane>>4)*8+j][n=lane&15].
#define ROWP 72   // padded LDS row stride in halfs (16B-aligned, breaks bank stride)
__global__ __launch_bounds__(256, 4)
void k_msg(const int* __restrict__ rowptr, int na, int nb,
           const float* __restrict__ efT, const float4* __restrict__ geo,
           const int* __restrict__ snd_s, const float4* __restrict__ pack,
           const _Float16* __restrict__ B1f, const _Float16* __restrict__ B2f,
           const _Float16* __restrict__ B3f, float2* __restrict__ msg,
           int cap, int E) {
    __shared__ _Float16 a2[4 * 16 * ROWP];
    __shared__ _Float16 a3[4 * 16 * ROWP];
    const int tid = threadIdx.x;
    const int lane = tid & 63;
    const int wave = tid >> 6;
    const int quad = lane >> 4;
    const int col = lane & 15;
    const int Jlo = rowptr[na], Jhi = rowptr[nb];
    const int j0 = Jlo + blockIdx.x * 64 + wave * 16;   // first edge of this wave

    _Float16* a2w = a2 + wave * 16 * ROWP;
    _Float16* a3w = a3 + wave * 16 * ROWP;

    // ---- stage 1: h1 = silu(ef @ RW1) via MFMA (K padded 8->32) ----
    half8 aef;
    #pragma unroll
    for (int k = 0; k < 8; k++) aef[k] = (_Float16)0.0f;
    if (quad == 0) {
        int je = j0 + col;
        if (je < Jhi) {
            #pragma unroll
            for (int k = 0; k < 8; k++) aef[k] = (_Float16)efT[(size_t)k * E + je];
        }
    }
    {
        floatx4 c1[4];
        #pragma unroll
        for (int nt = 0; nt < 4; nt++) {
            c1[nt] = (floatx4){0.0f, 0.0f, 0.0f, 0.0f};
            half8 b = *(const half8*)(B1f + ((size_t)nt * 64 + lane) * 8);
            c1[nt] = __builtin_amdgcn_mfma_f32_16x16x32_f16(aef, b, c1[nt], 0, 0, 0);
        }
        #pragma unroll
        for (int nt = 0; nt < 4; nt++)
            #pragma unroll
            for (int r = 0; r < 4; r++)
                a2w[(quad * 4 + r) * ROWP + nt * 16 + col] = (_Float16)siluf(c1[nt][r]);
    }
    __syncthreads();

    // ---- stage 2: h2 = silu(h1 @ RW2) ----
    {
        half8 af0 = *(const half8*)&a2w[col * ROWP + quad * 8];
        half8 af1 = *(const half8*)&a2w[col * ROWP + 32 + quad * 8];
        floatx4 c2[4];
        #pragma unroll
        for (int nt = 0; nt < 4; nt++) {
            c2[nt] = (floatx4){0.0f, 0.0f, 0.0f, 0.0f};
            half8 b0 = *(const half8*)(B2f + (((size_t)0 * 4 + nt) * 64 + lane) * 8);
            half8 b1 = *(const half8*)(B2f + (((size_t)1 * 4 + nt) * 64 + lane) * 8);
            c2[nt] = __builtin_amdgcn_mfma_f32_16x16x32_f16(af0, b0, c2[nt], 0, 0, 0);
            c2[nt] = __builtin_amdgcn_mfma_f32_16x16x32_f16(af1, b1, c2[nt], 0, 0, 0);
        }
        #pragma unroll
        for (int nt = 0; nt < 4; nt++)
            #pragma unroll
            for (int r = 0; r < 4; r++)
                a3w[(quad * 4 + r) * ROWP + nt * 16 + col] = (_Float16)siluf(c2[nt][r]);
    }
    __syncthreads();

    // ---- stage 3: w = h2 @ RW3, per 16-channel block, fused message epilogue ----
    const float inv32 = 1.0f / 32.0f;
    const float is3 = 0.5773502691896258f;   // 1/sqrt(3)
    const float is2 = 0.7071067811865476f;   // 1/sqrt(2)
    half8 a3f0 = *(const half8*)&a3w[col * ROWP + quad * 8];
    half8 a3f1 = *(const half8*)&a3w[col * ROWP + 32 + quad * 8];

    for (int cb = 0; cb < 4; cb++) {
        floatx4 acc[5];
        #pragma unroll
        for (int q = 0; q < 5; q++) {
            acc[q] = (floatx4){0.0f, 0.0f, 0.0f, 0.0f};
            int nt = q * 4 + cb;
            half8 b0 = *(const half8*)(B3f + (((size_t)0 * 20 + nt) * 64 + lane) * 8);
            half8 b1 = *(const half8*)(B3f + (((size_t)1 * 20 + nt) * 64 + lane) * 8);
            acc[q] = __builtin_amdgcn_mfma_f32_16x16x32_f16(a3f0, b0, acc[q], 0, 0, 0);
            acc[q] = __builtin_amdgcn_mfma_f32_16x16x32_f16(a3f1, b1, acc[q], 0, 0, 0);
        }
        const int c = cb * 16 + col;
        #pragma unroll
        for (int r = 0; r < 4; r++) {
            int m = quad * 4 + r;
            int jj = j0 + m;
            if (jj < Jhi) {
                int idx = jj - Jlo;
                if (idx < cap) {
                    int snd = snd_s[jj];
                    float4 g = geo[jj];
                    float4 pv = pack[(size_t)snd * 64 + c];   // (s_up, v0, v1, v2)
                    float w00 = acc[0][r], w110 = acc[1][r], w011 = acc[2][r];
                    float w101 = acc[3][r], w111 = acc[4][r];
                    float dvy = pv.y * g.x + pv.z * g.y + pv.w * g.z;
                    float m0 = (w00 * pv.x + w110 * dvy * is3) * inv32;
                    float cxv = pv.z * g.z - pv.w * g.y;
                    float cyv = pv.w * g.x - pv.y * g.z;
                    float czv = pv.y * g.y - pv.z * g.x;
                    float m1x = (w011 * pv.x * g.x + w101 * pv.y + w111 * cxv * is2) * inv32;
                    float m1y = (w011 * pv.x * g.y + w101 * pv.z + w111 * cyv * is2) * inv32;
                    float m1z = (w011 * pv.x * g.z + w101 * pv.w + w111 * czv * is2) * inv32;
                    union { __half2 h; float f; } ua, ub;
                    ua.h = __floats2half2_rn(m0, m1x);
                    ub.h = __floats2half2_rn(m1y, m1z);
                    msg[(size_t)idx * 64 + c] = make_float2(ua.f, ub.f);
                }
            }
        }
    }
}

// ---------------- CSR aggregation: wave per node, lane = channel ----------------
__global__ void k_agg(const float2* __restrict__ msg, const int* __restrict__ rowptr,
                      float* __restrict__ agg0, float* __restrict__ agg1,
                      int na, int nb, int cap) {
    int n = na + blockIdx.x * 4 + (threadIdx.x >> 6);
    int lane = threadIdx.x & 63;
    if (n >= nb) return;
    int Jlo = rowptr[na];
    int j0 = rowptr[n], j1 = rowptr[n + 1];
    float a0 = 0.0f, a1 = 0.0f, a2 = 0.0f, a3 = 0.0f;
    for (int j = j0; j < j1; j++) {
        int idx = j - Jlo;
        if (idx >= cap) break;
        float2 m = msg[(size_t)idx * 64 + lane];
        union { float f; __half2 h; } ua, ub;
        ua.f = m.x; ub.f = m.y;
        float2 fa = __half22float2(ua.h);
        float2 fb = __half22float2(ub.h);
        a0 += fa.x; a1 += fa.y; a2 += fb.x; a3 += fb.y;
    }
    size_t nbase = (size_t)n;
    agg0[nbase * 64 + lane] = a0;
    agg1[nbase * 192 + lane] = a1;
    agg1[nbase * 192 + 64 + lane] = a2;
    agg1[nbase * 192 + 128 + lane] = a3;
}

// ---------------- species-dependent skip connections (wave = node) ----------------
__global__ void k_sc(const float* __restrict__ s, const float* __restrict__ v,
                     const int* __restrict__ species, const float* __restrict__ Wsc_s,
                     const float* __restrict__ Wsc_v, float* __restrict__ sc_s,
                     float* __restrict__ sc_v, int N) {
    int n = blockIdx.x;
    if (n >= N) return;
    int lane = threadIdx.x;
    int z = species[n];
    const float* Ws = Wsc_s + (size_t)z * 4096;
    const float* Wv = Wsc_v + (size_t)z * 4096;
    size_t nb = (size_t)n;
    float sreg = s[nb * 64 + lane];
    float acc = 0.0f;
    for (int c = 0; c < 64; c++)
        acc = fmaf(__shfl(sreg, c), Ws[c * 64 + lane], acc);
    sc_s[nb * 64 + lane] = acc;
    for (int x = 0; x < 3; x++) {
        float vreg = v[nb * 192 + x * 64 + lane];
        float av = 0.0f;
        for (int c = 0; c < 64; c++)
            av = fmaf(__shfl(vreg, c), Wv[c * 64 + lane], av);
        sc_v[nb * 192 + x * 64 + lane] = av;
    }
}

// ---------------- prod_s -> new s + output slot ----------------
__global__ void k_prod_s(const float* __restrict__ ms, const float* __restrict__ mv,
                         const float* __restrict__ P0l, const int* __restrict__ species,
                         const float* __restrict__ Wp, const float* __restrict__ sc_s,
                         float* __restrict__ s, float* __restrict__ out,
                         int N, int layer, int L) {
    __shared__ float lds[64 * 65];
    int lane = threadIdx.x;
    int n0 = blockIdx.x * 64;
    int nv = min(64, N - n0);
    for (int r = 0; r < nv; r++) {
        size_t n = n0 + r;
        int z = species[n];
        float msv = ms[n * 64 + lane];
        float a = mv[n * 192 + lane];
        float b = mv[n * 192 + 64 + lane];
        float cq = mv[n * 192 + 128 + lane];
        float mq = a * a + b * b + cq * cq;
        const float* p = P0l + ((size_t)z * 64 + lane) * 3;
        lds[r * 65 + lane] = p[0] * msv + p[1] * msv * msv + p[2] * mq;
    }
    __syncthreads();
    float acc[64];
    #pragma unroll
    for (int d = 0; d < 64; d++) acc[d] = 0.0f;
    for (int c = 0; c < 64; c++) {
        float x = lds[lane * 65 + c];
        const float* wr = Wp + c * 64;
        #pragma unroll
        for (int d = 0; d < 64; d++) acc[d] = fmaf(x, wr[d], acc[d]);
    }
    __syncthreads();
    #pragma unroll
    for (int d = 0; d < 64; d++) lds[lane * 65 + d] = acc[d];
    __syncthreads();
    for (int r = 0; r < nv; r++) {
        size_t n = n0 + r;
        float val = lds[r * 65 + lane] + sc_s[n * 64 + lane];
        s[n * 64 + lane] = val;
        out[n * (size_t)(L * 64) + layer * 64 + lane] = val;
    }
}

// ---------------- prod_v -> new v ----------------
__global__ void k_prod_v(const float* __restrict__ ms, const float* __restrict__ mv,
                         const float* __restrict__ P1l, const int* __restrict__ species,
                         const float* __restrict__ Wp, const float* __restrict__ sc_v,
                         float* __restrict__ v, int N) {
    __shared__ float lds[64 * 65];
    int lane = threadIdx.x;
    int n0 = blockIdx.x * 64;
    int nv = min(64, N - n0);
    for (int x = 0; x < 3; x++) {
        for (int r = 0; r < nv; r++) {
            size_t n = n0 + r;
            int z = species[n];
            float msv = ms[n * 64 + lane];
            float mvv = mv[n * 192 + x * 64 + lane];
            const float* q = P1l + ((size_t)z * 64 + lane) * 2;
            lds[r * 65 + lane] = (q[0] + q[1] * msv) * mvv;
        }
        __syncthreads();
        float acc[64];
        #pragma unroll
        for (int d = 0; d < 64; d++) acc[d] = 0.0f;
        for (int c = 0; c < 64; c++) {
            float xx = lds[lane * 65 + c];
            const float* wr = Wp + c * 64;
            #pragma unroll
            for (int d = 0; d < 64; d++) acc[d] = fmaf(xx, wr[d], acc[d]);
        }
        __syncthreads();
        #pragma unroll
        for (int d = 0; d < 64; d++) lds[lane * 65 + d] = acc[d];
        __syncthreads();
        for (int r = 0; r < nv; r++) {
            size_t n = n0 + r;
            v[n * 192 + x * 64 + lane] = lds[r * 65 + lane] + sc_v[n * 192 + x * 64 + lane];
        }
        __syncthreads();
    }
}

extern "C" void kernel_launch(void* const* d_in, const int* in_sizes, int n_in,
                              void* d_out, int out_size, void* d_ws, size_t ws_size,
                              hipStream_t stream) {
    const float* node_attrs = (const float*)d_in[0];
    const float* atom_pos   = (const float*)d_in[1];
    const float* shifts     = (const float*)d_in[2];
    const float* W_embed    = (const float*)d_in[3];
    const float* Wup_s      = (const float*)d_in[4];
    const float* Wup_v      = (const float*)d_in[5];
    const float* RW1        = (const float*)d_in[6];
    const float* RW2        = (const float*)d_in[7];
    const float* RW3        = (const float*)d_in[8];
    const float* Wout_s     = (const float*)d_in[9];
    const float* Wout_v     = (const float*)d_in[10];
    const float* Wsc_s      = (const float*)d_in[11];
    const float* Wsc_v      = (const float*)d_in[12];
    const float* P0         = (const float*)d_in[13];
    const float* P1         = (const float*)d_in[14];
    const float* Wprod_s    = (const float*)d_in[15];
    const float* Wprod_v    = (const float*)d_in[16];
    const int*   ei         = (const int*)d_in[17];

    const int N = in_sizes[0] / 10;
    const int E = in_sizes[17] / 2;
    const int L = in_sizes[4] / 4096;
    float* out = (float*)d_out;

    char* wsb = (char*)d_ws;
    size_t off = 0;
    auto alloci = [&](size_t n) {
        int* p = (int*)(wsb + off);
        off = (off + n * 4 + 255) / 256 * 256;
        return p;
    };
    auto allocf = [&](size_t n) {
        float* p = (float*)(wsb + off);
        off = (off + n * 4 + 255) / 256 * 256;
        return p;
    };
    auto alloch = [&](size_t n) {
        _Float16* p = (_Float16*)(wsb + off);
        off = (off + n * 2 + 255) / 256 * 256;
        return p;
    };
    int* species = alloci(N);
    int* deg     = alloci(N);
    int* rowptr  = alloci(N + 1);
    int* cursor  = alloci(N);
    int* perm    = alloci(E);
    int* snd_s   = alloci(E);
    float* s     = allocf((size_t)N * 64);
    float* v     = allocf((size_t)N * 192);
    float* agg0  = allocf((size_t)N * 64);   // reused in-place as ms
    float* agg1  = allocf((size_t)N * 192);  // reused in-place as mv
    float* geo   = allocf((size_t)E * 4);
    float* efT   = allocf((size_t)E * 8);
    float* pack  = allocf((size_t)N * 256);
    _Float16* B1f = alloch((size_t)L * 2048);
    _Float16* B2f = alloch((size_t)L * 4096);
    _Float16* B3f = alloch((size_t)L * 20480);
    // sc_s/sc_v alias pack (lifetimes disjoint within a layer)
    float* sc_s  = pack;
    float* sc_v  = pack + (size_t)N * 64;

    // pick NCHUNK at runtime from ws_size (constant per session -> graph-safe)
    int NCHUNK = 16;
    int cap = 0;
    {
        const int cands[8] = {1, 2, 3, 4, 6, 8, 12, 16};
        for (int ci = 0; ci < 8; ci++) {
            int c = cands[ci];
            int thiscap = (c == 1) ? E : (E / c) * 5 / 4 + 256;
            size_t need = off + (size_t)thiscap * 512;  // 128 floats * 4B per edge
            if (need <= ws_size) { NCHUNK = c; cap = thiscap; break; }
        }
        if (cap == 0) { NCHUNK = 16; cap = (E / 16) * 5 / 4 + 256; }
    }
    float* msg = allocf((size_t)cap * 128);   // fp16 half4 = float2 per (edge,ch)
    (void)n_in; (void)out_size;

    const int NT = (N + 63) / 64;
    const int ET = (E + 63) / 64;
    const int EB = (E + 255) / 256;
    const int MT = (cap + 63) / 64;            // k_msg: 64 edges per 256-thread block

    k_init<<<NT, 64, 0, stream>>>(node_attrs, W_embed, species, deg, s, v, N);
    k_hist<<<EB, 256, 0, stream>>>(ei, deg, E);
    k_scan<<<1, 1024, 0, stream>>>(deg, rowptr, cursor, N);
    k_perm<<<EB, 256, 0, stream>>>(ei, cursor, perm, E);
    k_geom<<<ET, 64, 0, stream>>>(ei, perm, atom_pos, shifts,
                                  (float4*)geo, efT, snd_s, E);
    k_wprep<<<52 * L, 64, 0, stream>>>(RW1, RW2, RW3, B1f, B2f, B3f);

    int nbound[17];
    for (int k = 0; k <= NCHUNK; k++) nbound[k] = (int)((long long)N * k / NCHUNK);

    for (int i = 0; i < L; i++) {
        k_4mv<<<NT, 64, 0, stream>>>(s, v, Wup_s + (size_t)i * 4096, Wup_v + (size_t)i * 4096,
                                     nullptr, nullptr, pack, N);
        for (int k = 0; k < NCHUNK; k++) {
            int na = nbound[k], nb = nbound[k + 1];
            k_msg<<<MT, 256, 0, stream>>>(rowptr, na, nb, efT, (const float4*)geo, snd_s,
                                          (const float4*)pack,
                                          B1f + (size_t)i * 2048, B2f + (size_t)i * 4096,
                                          B3f + (size_t)i * 20480, (float2*)msg, cap, E);
            int cnt = nb - na;
            k_agg<<<(cnt + 3) / 4, 256, 0, stream>>>((const float2*)msg, rowptr,
                                                     agg0, agg1, na, nb, cap);
        }
        k_sc<<<N, 64, 0, stream>>>(s, v, species, Wsc_s + (size_t)i * 40960,
                                   Wsc_v + (size_t)i * 40960, sc_s, sc_v, N);
        k_4mv<<<NT, 64, 0, stream>>>(agg0, agg1, Wout_s + (size_t)i * 4096,
                                     Wout_v + (size_t)i * 4096, agg0, agg1, nullptr, N);
        k_prod_s<<<NT, 64, 0, stream>>>(agg0, agg1, P0 + (size_t)i * 1920, species,
                                        Wprod_s + (size_t)i * 4096, sc_s, s, out, N, i, L);
        k_prod_v<<<NT, 64, 0, stream>>>(agg0, agg1, P1 + (size_t)i * 1280, species,
                                        Wprod_v + (size_t)i * 4096, sc_v, v, N);
    }
}

// Round 8
// 742.977 us; speedup vs baseline: 13.1034x; 1.5311x over previous
//
#include <hip/hip_runtime.h>
#include <hip/hip_bf16.h>
#include <hip/hip_fp16.h>

typedef _Float16 half8 __attribute__((ext_vector_type(8)));
typedef float floatx4 __attribute__((ext_vector_type(4)));

__device__ __forceinline__ float siluf(float x) {
    return x / (1.0f + __expf(-x));
}

// ---------------- species per node + histogram ----------------
__global__ void k_species(const float* __restrict__ attrs, int* __restrict__ species_o,
                          int* __restrict__ zcount, int N) {
    int n = blockIdx.x * 256 + threadIdx.x;
    if (n >= N) return;
    int z = 0;
    #pragma unroll
    for (int k = 1; k < 10; k++) if (attrs[n * 10 + k] > 0.5f) z = k;
    species_o[n] = z;
    atomicAdd(&zcount[z], 1);
}

__global__ void k_zscan(const int* __restrict__ zcount, int* __restrict__ zcur) {
    if (threadIdx.x == 0) {
        int run = 0;
        for (int z = 0; z < 10; z++) { zcur[z] = run; run += zcount[z]; }
    }
}

__global__ void k_zperm(const int* __restrict__ species_o, int* __restrict__ zcur,
                        int* __restrict__ perm_n, int* __restrict__ inv_n, int N) {
    int n = blockIdx.x * 256 + threadIdx.x;
    if (n >= N) return;
    int pos = atomicAdd(&zcur[species_o[n]], 1);
    perm_n[pos] = n;
    inv_n[n] = pos;
}

// ---------------- init state in SPECIES-SORTED node order ----------------
__global__ void k_init(const int* __restrict__ perm_n, const int* __restrict__ species_o,
                       const float* __restrict__ Wemb, int* __restrict__ species_s,
                       int* __restrict__ origid, float* __restrict__ s,
                       float* __restrict__ v, int N) {
    int p = blockIdx.x;
    if (p >= N) return;
    int lane = threadIdx.x;
    int n = perm_n[p];
    int z = species_o[n];
    if (lane == 0) { species_s[p] = z; origid[p] = n; }
    s[(size_t)p * 64 + lane] = Wemb[z * 64 + lane];
    v[(size_t)p * 192 + lane] = 0.0f;
    v[(size_t)p * 192 + 64 + lane] = 0.0f;
    v[(size_t)p * 192 + 128 + lane] = 0.0f;
}

// ---------------- counting sort of edges by (sorted) receiver ----------------
__global__ void k_hist(const int* __restrict__ ei, const int* __restrict__ inv_n,
                       int* __restrict__ deg, int E) {
    int e = blockIdx.x * 256 + threadIdx.x;
    if (e < E) atomicAdd(&deg[inv_n[ei[E + e]]], 1);
}

__global__ void k_scan(const int* __restrict__ deg, int* __restrict__ rowptr,
                       int* __restrict__ cursor, int N) {
    __shared__ int part[1024];
    int t = threadIdx.x;
    int chunk = (N + 1023) / 1024;
    int lo = t * chunk, hi = min(lo + chunk, N);
    int sum = 0;
    for (int i = lo; i < hi; i++) sum += deg[i];
    part[t] = sum;
    __syncthreads();
    for (int off = 1; off < 1024; off <<= 1) {
        int add = (t >= off) ? part[t - off] : 0;
        __syncthreads();
        part[t] += add;
        __syncthreads();
    }
    int run = (t > 0) ? part[t - 1] : 0;
    for (int i = lo; i < hi; i++) { rowptr[i] = run; cursor[i] = run; run += deg[i]; }
    if (t == 1023) rowptr[N] = part[1023];
}

__global__ void k_eperm(const int* __restrict__ ei, const int* __restrict__ inv_n,
                        int* __restrict__ cursor, int* __restrict__ perm, int E) {
    int e = blockIdx.x * 256 + threadIdx.x;
    if (e < E) {
        int r = inv_n[ei[E + e]];
        int pos = atomicAdd(&cursor[r], 1);
        perm[pos] = e;
    }
}

// ---------------- geometry + radial basis on SORTED edge order ----------------
__global__ void k_geom(const int* __restrict__ ei, const int* __restrict__ perm,
                       const int* __restrict__ inv_n, const float* __restrict__ pos,
                       const float* __restrict__ shifts, float4* __restrict__ geo,
                       float* __restrict__ efT, int* __restrict__ snd_s, int E) {
    int j = blockIdx.x * 64 + threadIdx.x;
    if (j >= E) return;
    int e = perm[j];
    int snd = ei[e], rcv = ei[E + e];
    float dx = pos[rcv * 3 + 0] - pos[snd * 3 + 0] + shifts[e * 3 + 0];
    float dy = pos[rcv * 3 + 1] - pos[snd * 3 + 1] + shifts[e * 3 + 1];
    float dz = pos[rcv * 3 + 2] - pos[snd * 3 + 2] + shifts[e * 3 + 2];
    float r = sqrtf(dx * dx + dy * dy + dz * dz);
    float rin = 1.0f / (r + 1e-9f);
    const float SQ3 = 1.7320508075688772f;
    geo[j] = make_float4(SQ3 * dx * rin, SQ3 * dy * rin, SQ3 * dz * rin, 0.0f);
    snd_s[j] = inv_n[snd];
    float u = r * 0.2f;
    float env = 0.0f;
    if (u < 1.0f) {
        float u2 = u * u;
        float u6 = u2 * u2 * u2;
        env = 1.0f - 28.0f * u6 + 48.0f * u6 * u - 21.0f * u6 * u2;
    }
    const float PIF = 3.14159265358979f;
    float x = PIF * u;
    float sp = __sinf(x), cp = __cosf(x);
    float coef = 0.6324555320336759f * rin * env;
    float sm1 = 0.0f, scur = sp, twoc = 2.0f * cp;
    #pragma unroll
    for (int k = 0; k < 8; k++) {
        efT[k * (size_t)E + j] = coef * scur;
        float nxt = twoc * scur - sm1;
        sm1 = scur; scur = nxt;
    }
}

// -------- weight prep (edge MLP): RW1/RW2/RW3 -> fp16 B-frag (16x16x32 MFMA) --------
__global__ void k_wprep(const float* __restrict__ RW1, const float* __restrict__ RW2,
                        const float* __restrict__ RW3, _Float16* __restrict__ B1f,
                        _Float16* __restrict__ B2f, _Float16* __restrict__ B3f) {
    int lane = threadIdx.x;
    int t = blockIdx.x;
    int layer = t / 52;
    int tt = t % 52;
    int quad = lane >> 4, colx = lane & 15;
    if (tt < 4) {
        int nt = tt;
        const float* W = RW1 + (size_t)layer * 512;
        _Float16* dst = B1f + (size_t)layer * 2048 + ((size_t)nt * 64 + lane) * 8;
        #pragma unroll
        for (int j = 0; j < 8; j++) {
            int k = quad * 8 + j, n = nt * 16 + colx;
            dst[j] = (k < 8) ? (_Float16)W[k * 64 + n] : (_Float16)0.0f;
        }
    } else if (tt < 12) {
        int u = tt - 4;
        int kt = u >> 2, nt = u & 3;
        const float* W = RW2 + (size_t)layer * 4096;
        _Float16* dst = B2f + (size_t)layer * 4096 + (((size_t)kt * 4 + nt) * 64 + lane) * 8;
        #pragma unroll
        for (int j = 0; j < 8; j++) {
            int k = kt * 32 + quad * 8 + j, n = nt * 16 + colx;
            dst[j] = (_Float16)W[k * 64 + n];
        }
    } else {
        int u = tt - 12;
        int kt = u / 20, nt = u % 20;
        const float* W = RW3 + (size_t)layer * 20480;
        _Float16* dst = B3f + (size_t)layer * 20480 + (((size_t)kt * 20 + nt) * 64 + lane) * 8;
        #pragma unroll
        for (int j = 0; j < 8; j++) {
            int k = kt * 32 + quad * 8 + j, n = nt * 16 + colx;
            dst[j] = (_Float16)W[k * 320 + n];
        }
    }
}

// -------- weight prep (node mats): 64x64 fp32 -> B-frag fp16. 26 mats per layer -----
// layout per layer: [0]up_s [1]up_v [2]out_s [3]out_v [4]prod_s [5]prod_v
//                   [6..15] sc_s(z) [16..25] sc_v(z); each 4096 halfs
__global__ void k_wprep_node(const float* __restrict__ Wup_s, const float* __restrict__ Wup_v,
                             const float* __restrict__ Wout_s, const float* __restrict__ Wout_v,
                             const float* __restrict__ Wprod_s, const float* __restrict__ Wprod_v,
                             const float* __restrict__ Wsc_s, const float* __restrict__ Wsc_v,
                             _Float16* __restrict__ Bmats) {
    int mid = blockIdx.x;
    int layer = mid / 26, m = mid % 26;
    const float* src;
    if (m == 0)      src = Wup_s  + (size_t)layer * 4096;
    else if (m == 1) src = Wup_v  + (size_t)layer * 4096;
    else if (m == 2) src = Wout_s + (size_t)layer * 4096;
    else if (m == 3) src = Wout_v + (size_t)layer * 4096;
    else if (m == 4) src = Wprod_s + (size_t)layer * 4096;
    else if (m == 5) src = Wprod_v + (size_t)layer * 4096;
    else if (m < 16) src = Wsc_s + (size_t)layer * 40960 + (size_t)(m - 6) * 4096;
    else             src = Wsc_v + (size_t)layer * 40960 + (size_t)(m - 16) * 4096;
    _Float16* dst = Bmats + (size_t)mid * 4096;
    int lane = threadIdx.x, quad = lane >> 4, colx = lane & 15;
    for (int t = 0; t < 8; t++) {
        int kt = t >> 2, nt = t & 3;
        #pragma unroll
        for (int j = 0; j < 8; j++) {
            int k = kt * 32 + quad * 8 + j, n = nt * 16 + colx;
            dst[(size_t)t * 512 + lane * 8 + j] = (_Float16)src[k * 64 + n];
        }
    }
}

// helper: load A-frag (8 ch of one node) from planar fp32, fp16-convert
__device__ __forceinline__ half8 loadA(const float* __restrict__ base, bool valid) {
    half8 a;
    if (valid) {
        float4 f0 = ((const float4*)base)[0];
        float4 f1 = ((const float4*)base)[1];
        a[0]=(_Float16)f0.x; a[1]=(_Float16)f0.y; a[2]=(_Float16)f0.z; a[3]=(_Float16)f0.w;
        a[4]=(_Float16)f1.x; a[5]=(_Float16)f1.y; a[6]=(_Float16)f1.z; a[7]=(_Float16)f1.w;
    } else {
        #pragma unroll
        for (int j = 0; j < 8; j++) a[j] = (_Float16)0.0f;
    }
    return a;
}

// ---- node kernel A: up-projection (pack) + species skip (scp), MFMA, wave=16 nodes --
__global__ __launch_bounds__(256, 4)
void k_nodeA(const float* __restrict__ s, const float* __restrict__ v,
             const int* __restrict__ species,
             const _Float16* __restrict__ Bup_s, const _Float16* __restrict__ Bup_v,
             const _Float16* __restrict__ Bsc_s, const _Float16* __restrict__ Bsc_v,
             const float* __restrict__ Wsc_s32, const float* __restrict__ Wsc_v32,
             float4* __restrict__ pack, float4* __restrict__ scp, int N) {
    const int tid = threadIdx.x;
    const int lane = tid & 63, wave = tid >> 6;
    const int quad = lane >> 4, col = lane & 15;
    const int n0 = blockIdx.x * 64 + wave * 16;
    if (n0 >= N) return;   // no barriers in this kernel

    half8 as[2], av0[2], av1[2], av2[2];
    int node = n0 + col;
    bool vn = node < N;
    const float* sp = s + (size_t)(vn ? node : 0) * 64;
    const float* vp = v + (size_t)(vn ? node : 0) * 192;
    #pragma unroll
    for (int kt = 0; kt < 2; kt++) {
        int kb = kt * 32 + quad * 8;
        as[kt]  = loadA(sp + kb, vn);
        av0[kt] = loadA(vp + kb, vn);
        av1[kt] = loadA(vp + 64 + kb, vn);
        av2[kt] = loadA(vp + 128 + kb, vn);
    }

    // up-projection -> pack
    #pragma unroll
    for (int nt = 0; nt < 4; nt++) {
        floatx4 cs = {0,0,0,0}, c0 = {0,0,0,0}, c1 = {0,0,0,0}, c2 = {0,0,0,0};
        #pragma unroll
        for (int kt = 0; kt < 2; kt++) {
            half8 bs = *(const half8*)(Bup_s + (((size_t)kt * 4 + nt) * 64 + lane) * 8);
            half8 bv = *(const half8*)(Bup_v + (((size_t)kt * 4 + nt) * 64 + lane) * 8);
            cs = __builtin_amdgcn_mfma_f32_16x16x32_f16(as[kt],  bs, cs, 0, 0, 0);
            c0 = __builtin_amdgcn_mfma_f32_16x16x32_f16(av0[kt], bv, c0, 0, 0, 0);
            c1 = __builtin_amdgcn_mfma_f32_16x16x32_f16(av1[kt], bv, c1, 0, 0, 0);
            c2 = __builtin_amdgcn_mfma_f32_16x16x32_f16(av2[kt], bv, c2, 0, 0, 0);
        }
        #pragma unroll
        for (int r = 0; r < 4; r++) {
            int n = n0 + quad * 4 + r;
            if (n < N)
                pack[(size_t)n * 64 + nt * 16 + col] = make_float4(cs[r], c0[r], c1[r], c2[r]);
        }
    }

    // species skip connection -> scp
    int zlo = species[n0];
    int zhi = species[min(n0 + 15, N - 1)];
    if (zlo == zhi) {
        const _Float16* Bs = Bsc_s + (size_t)zlo * 4096;
        const _Float16* Bv = Bsc_v + (size_t)zlo * 4096;
        #pragma unroll
        for (int nt = 0; nt < 4; nt++) {
            floatx4 cs = {0,0,0,0}, c0 = {0,0,0,0}, c1 = {0,0,0,0}, c2 = {0,0,0,0};
            #pragma unroll
            for (int kt = 0; kt < 2; kt++) {
                half8 bs = *(const half8*)(Bs + (((size_t)kt * 4 + nt) * 64 + lane) * 8);
                half8 bv = *(const half8*)(Bv + (((size_t)kt * 4 + nt) * 64 + lane) * 8);
                cs = __builtin_amdgcn_mfma_f32_16x16x32_f16(as[kt],  bs, cs, 0, 0, 0);
                c0 = __builtin_amdgcn_mfma_f32_16x16x32_f16(av0[kt], bv, c0, 0, 0, 0);
                c1 = __builtin_amdgcn_mfma_f32_16x16x32_f16(av1[kt], bv, c1, 0, 0, 0);
                c2 = __builtin_amdgcn_mfma_f32_16x16x32_f16(av2[kt], bv, c2, 0, 0, 0);
            }
            #pragma unroll
            for (int r = 0; r < 4; r++) {
                int n = n0 + quad * 4 + r;
                if (n < N)
                    scp[(size_t)n * 64 + nt * 16 + col] = make_float4(cs[r], c0[r], c1[r], c2[r]);
            }
        }
    } else {
        // mixed-species tile (<= Z-1 = 9 tiles total): scalar fallback
        for (int m = 0; m < 16; m++) {
            int n = n0 + m;
            if (n >= N) break;
            int z = species[n];
            const float* Ws = Wsc_s32 + (size_t)z * 4096;
            const float* Wv = Wsc_v32 + (size_t)z * 4096;
            float sv = s[(size_t)n * 64 + lane];
            float w0 = v[(size_t)n * 192 + lane];
            float w1 = v[(size_t)n * 192 + 64 + lane];
            float w2 = v[(size_t)n * 192 + 128 + lane];
            float a = 0, b0 = 0, b1 = 0, b2 = 0;
            for (int c = 0; c < 64; c++) {
                float ws = Ws[c * 64 + lane], wv = Wv[c * 64 + lane];
                a  = fmaf(__shfl(sv, c), ws, a);
                b0 = fmaf(__shfl(w0, c), wv, b0);
                b1 = fmaf(__shfl(w1, c), wv, b1);
                b2 = fmaf(__shfl(w2, c), wv, b2);
            }
            scp[(size_t)n * 64 + lane] = make_float4(a, b0, b1, b2);
        }
    }
}

// ---- message kernel: MFMA edge-MLP (validated round 7), wave = 16 edges ----
#define ROWP 72
__global__ __launch_bounds__(256, 4)
void k_msg(const int* __restrict__ rowptr, int na, int nb,
           const float* __restrict__ efT, const float4* __restrict__ geo,
           const int* __restrict__ snd_s, const float4* __restrict__ pack,
           const _Float16* __restrict__ B1f, const _Float16* __restrict__ B2f,
           const _Float16* __restrict__ B3f, float2* __restrict__ msg,
           int cap, int E) {
    __shared__ _Float16 a2[4 * 16 * ROWP];
    __shared__ _Float16 a3[4 * 16 * ROWP];
    const int tid = threadIdx.x;
    const int lane = tid & 63;
    const int wave = tid >> 6;
    const int quad = lane >> 4;
    const int col = lane & 15;
    const int Jlo = rowptr[na], Jhi = rowptr[nb];
    const int j0 = Jlo + blockIdx.x * 64 + wave * 16;

    _Float16* a2w = a2 + wave * 16 * ROWP;
    _Float16* a3w = a3 + wave * 16 * ROWP;

    half8 aef;
    #pragma unroll
    for (int k = 0; k < 8; k++) aef[k] = (_Float16)0.0f;
    if (quad == 0) {
        int je = j0 + col;
        if (je < Jhi) {
            #pragma unroll
            for (int k = 0; k < 8; k++) aef[k] = (_Float16)efT[(size_t)k * E + je];
        }
    }
    {
        floatx4 c1[4];
        #pragma unroll
        for (int nt = 0; nt < 4; nt++) {
            c1[nt] = (floatx4){0.0f, 0.0f, 0.0f, 0.0f};
            half8 b = *(const half8*)(B1f + ((size_t)nt * 64 + lane) * 8);
            c1[nt] = __builtin_amdgcn_mfma_f32_16x16x32_f16(aef, b, c1[nt], 0, 0, 0);
        }
        #pragma unroll
        for (int nt = 0; nt < 4; nt++)
            #pragma unroll
            for (int r = 0; r < 4; r++)
                a2w[(quad * 4 + r) * ROWP + nt * 16 + col] = (_Float16)siluf(c1[nt][r]);
    }
    __syncthreads();

    {
        half8 af0 = *(const half8*)&a2w[col * ROWP + quad * 8];
        half8 af1 = *(const half8*)&a2w[col * ROWP + 32 + quad * 8];
        floatx4 c2[4];
        #pragma unroll
        for (int nt = 0; nt < 4; nt++) {
            c2[nt] = (floatx4){0.0f, 0.0f, 0.0f, 0.0f};
            half8 b0 = *(const half8*)(B2f + (((size_t)0 * 4 + nt) * 64 + lane) * 8);
            half8 b1 = *(const half8*)(B2f + (((size_t)1 * 4 + nt) * 64 + lane) * 8);
            c2[nt] = __builtin_amdgcn_mfma_f32_16x16x32_f16(af0, b0, c2[nt], 0, 0, 0);
            c2[nt] = __builtin_amdgcn_mfma_f32_16x16x32_f16(af1, b1, c2[nt], 0, 0, 0);
        }
        #pragma unroll
        for (int nt = 0; nt < 4; nt++)
            #pragma unroll
            for (int r = 0; r < 4; r++)
                a3w[(quad * 4 + r) * ROWP + nt * 16 + col] = (_Float16)siluf(c2[nt][r]);
    }
    __syncthreads();

    const float inv32 = 1.0f / 32.0f;
    const float is3 = 0.5773502691896258f;
    const float is2 = 0.7071067811865476f;
    half8 a3f0 = *(const half8*)&a3w[col * ROWP + quad * 8];
    half8 a3f1 = *(const half8*)&a3w[col * ROWP + 32 + quad * 8];

    for (int cb = 0; cb < 4; cb++) {
        floatx4 acc[5];
        #pragma unroll
        for (int q = 0; q < 5; q++) {
            acc[q] = (floatx4){0.0f, 0.0f, 0.0f, 0.0f};
            int nt = q * 4 + cb;
            half8 b0 = *(const half8*)(B3f + (((size_t)0 * 20 + nt) * 64 + lane) * 8);
            half8 b1 = *(const half8*)(B3f + (((size_t)1 * 20 + nt) * 64 + lane) * 8);
            acc[q] = __builtin_amdgcn_mfma_f32_16x16x32_f16(a3f0, b0, acc[q], 0, 0, 0);
            acc[q] = __builtin_amdgcn_mfma_f32_16x16x32_f16(a3f1, b1, acc[q], 0, 0, 0);
        }
        const int c = cb * 16 + col;
        #pragma unroll
        for (int r = 0; r < 4; r++) {
            int m = quad * 4 + r;
            int jj = j0 + m;
            if (jj < Jhi) {
                int idx = jj - Jlo;
                if (idx < cap) {
                    int snd = snd_s[jj];
                    float4 g = geo[jj];
                    float4 pv = pack[(size_t)snd * 64 + c];
                    float w00 = acc[0][r], w110 = acc[1][r], w011 = acc[2][r];
                    float w101 = acc[3][r], w111 = acc[4][r];
                    float dvy = pv.y * g.x + pv.z * g.y + pv.w * g.z;
                    float m0 = (w00 * pv.x + w110 * dvy * is3) * inv32;
                    float cxv = pv.z * g.z - pv.w * g.y;
                    float cyv = pv.w * g.x - pv.y * g.z;
                    float czv = pv.y * g.y - pv.z * g.x;
                    float m1x = (w011 * pv.x * g.x + w101 * pv.y + w111 * cxv * is2) * inv32;
                    float m1y = (w011 * pv.x * g.y + w101 * pv.z + w111 * cyv * is2) * inv32;
                    float m1z = (w011 * pv.x * g.z + w101 * pv.w + w111 * czv * is2) * inv32;
                    union { __half2 h; float f; } ua, ub;
                    ua.h = __floats2half2_rn(m0, m1x);
                    ub.h = __floats2half2_rn(m1y, m1z);
                    msg[(size_t)idx * 64 + c] = make_float2(ua.f, ub.f);
                }
            }
        }
    }
}

// ---------------- CSR aggregation: wave per node, lane = channel ----------------
__global__ void k_agg(const float2* __restrict__ msg, const int* __restrict__ rowptr,
                      float* __restrict__ agg0, float* __restrict__ agg1,
                      int na, int nb, int cap) {
    int n = na + blockIdx.x * 4 + (threadIdx.x >> 6);
    int lane = threadIdx.x & 63;
    if (n >= nb) return;
    int Jlo = rowptr[na];
    int j0 = rowptr[n], j1 = rowptr[n + 1];
    float a0 = 0.0f, a1 = 0.0f, a2 = 0.0f, a3 = 0.0f;
    for (int j = j0; j < j1; j++) {
        int idx = j - Jlo;
        if (idx >= cap) break;
        float2 m = msg[(size_t)idx * 64 + lane];
        union { float f; __half2 h; } ua, ub;
        ua.f = m.x; ub.f = m.y;
        float2 fa = __half22float2(ua.h);
        float2 fb = __half22float2(ub.h);
        a0 += fa.x; a1 += fa.y; a2 += fb.x; a3 += fb.y;
    }
    size_t nbase = (size_t)n;
    agg0[nbase * 64 + lane] = a0;
    agg1[nbase * 192 + lane] = a1;
    agg1[nbase * 192 + 64 + lane] = a2;
    agg1[nbase * 192 + 128 + lane] = a3;
}

// ---- node kernel B: Wout MFMA -> P0/P1 epilogue -> LDS transpose -> Wprod MFMA -----
#define ROWPB 72
__global__ __launch_bounds__(256, 4)
void k_nodeB(const float* __restrict__ agg0, const float* __restrict__ agg1,
             const int* __restrict__ species, const int* __restrict__ origid,
             const _Float16* __restrict__ Bout_s, const _Float16* __restrict__ Bout_v,
             const _Float16* __restrict__ Bprod_s, const _Float16* __restrict__ Bprod_v,
             const float* __restrict__ P0l, const float* __restrict__ P1l,
             const float4* __restrict__ scp, float* __restrict__ s,
             float* __restrict__ v, float* __restrict__ out,
             int N, int layer, int Ltot) {
    __shared__ _Float16 lds[4 * 4 * 16 * ROWPB];   // [wave][comp][node16 * ROWPB]
    const int tid = threadIdx.x;
    const int lane = tid & 63, wave = tid >> 6;
    const int quad = lane >> 4, col = lane & 15;
    const int n0 = blockIdx.x * 64 + wave * 16;
    const bool act = n0 < N;
    _Float16* lw = lds + wave * 4 * 16 * ROWPB;

    if (act) {
        half8 as[2], av0[2], av1[2], av2[2];
        int node = n0 + col;
        bool vn = node < N;
        const float* ap = agg0 + (size_t)(vn ? node : 0) * 64;
        const float* vp = agg1 + (size_t)(vn ? node : 0) * 192;
        #pragma unroll
        for (int kt = 0; kt < 2; kt++) {
            int kb = kt * 32 + quad * 8;
            as[kt]  = loadA(ap + kb, vn);
            av0[kt] = loadA(vp + kb, vn);
            av1[kt] = loadA(vp + 64 + kb, vn);
            av2[kt] = loadA(vp + 128 + kb, vn);
        }
        #pragma unroll
        for (int nt = 0; nt < 4; nt++) {
            floatx4 cs = {0,0,0,0}, c0 = {0,0,0,0}, c1 = {0,0,0,0}, c2 = {0,0,0,0};
            #pragma unroll
            for (int kt = 0; kt < 2; kt++) {
                half8 bs = *(const half8*)(Bout_s + (((size_t)kt * 4 + nt) * 64 + lane) * 8);
                half8 bv = *(const half8*)(Bout_v + (((size_t)kt * 4 + nt) * 64 + lane) * 8);
                cs = __builtin_amdgcn_mfma_f32_16x16x32_f16(as[kt],  bs, cs, 0, 0, 0);
                c0 = __builtin_amdgcn_mfma_f32_16x16x32_f16(av0[kt], bv, c0, 0, 0, 0);
                c1 = __builtin_amdgcn_mfma_f32_16x16x32_f16(av1[kt], bv, c1, 0, 0, 0);
                c2 = __builtin_amdgcn_mfma_f32_16x16x32_f16(av2[kt], bv, c2, 0, 0, 0);
            }
            int ch = nt * 16 + col;
            #pragma unroll
            for (int r = 0; r < 4; r++) {
                int nl = quad * 4 + r;
                int n = n0 + nl;
                float ps = 0.0f, p0v = 0.0f, p1v = 0.0f, p2v = 0.0f;
                if (n < N) {
                    int z = species[n];
                    const float* p = P0l + ((size_t)z * 64 + ch) * 3;
                    const float* q = P1l + ((size_t)z * 64 + ch) * 2;
                    float msv = cs[r];
                    float m0 = c0[r], m1 = c1[r], m2 = c2[r];
                    ps = p[0] * msv + p[1] * msv * msv + p[2] * (m0 * m0 + m1 * m1 + m2 * m2);
                    float qq = q[0] + q[1] * msv;
                    p0v = qq * m0; p1v = qq * m1; p2v = qq * m2;
                }
                lw[0 * 16 * ROWPB + nl * ROWPB + ch] = (_Float16)ps;
                lw[1 * 16 * ROWPB + nl * ROWPB + ch] = (_Float16)p0v;
                lw[2 * 16 * ROWPB + nl * ROWPB + ch] = (_Float16)p1v;
                lw[3 * 16 * ROWPB + nl * ROWPB + ch] = (_Float16)p2v;
            }
        }
    }
    __syncthreads();
    if (act) {
        half8 as[2], av0[2], av1[2], av2[2];
        #pragma unroll
        for (int kt = 0; kt < 2; kt++) {
            int kb = kt * 32 + quad * 8;
            as[kt]  = *(const half8*)&lw[0 * 16 * ROWPB + col * ROWPB + kb];
            av0[kt] = *(const half8*)&lw[1 * 16 * ROWPB + col * ROWPB + kb];
            av1[kt] = *(const half8*)&lw[2 * 16 * ROWPB + col * ROWPB + kb];
            av2[kt] = *(const half8*)&lw[3 * 16 * ROWPB + col * ROWPB + kb];
        }
        #pragma unroll
        for (int nt = 0; nt < 4; nt++) {
            floatx4 cs = {0,0,0,0}, c0 = {0,0,0,0}, c1 = {0,0,0,0}, c2 = {0,0,0,0};
            #pragma unroll
            for (int kt = 0; kt < 2; kt++) {
                half8 bs = *(const half8*)(Bprod_s + (((size_t)kt * 4 + nt) * 64 + lane) * 8);
                half8 bv = *(const half8*)(Bprod_v + (((size_t)kt * 4 + nt) * 64 + lane) * 8);
                cs = __builtin_amdgcn_mfma_f32_16x16x32_f16(as[kt],  bs, cs, 0, 0, 0);
                c0 = __builtin_amdgcn_mfma_f32_16x16x32_f16(av0[kt], bv, c0, 0, 0, 0);
                c1 = __builtin_amdgcn_mfma_f32_16x16x32_f16(av1[kt], bv, c1, 0, 0, 0);
                c2 = __builtin_amdgcn_mfma_f32_16x16x32_f16(av2[kt], bv, c2, 0, 0, 0);
            }
            int ch = nt * 16 + col;
            #pragma unroll
            for (int r = 0; r < 4; r++) {
                int n = n0 + quad * 4 + r;
                if (n < N) {
                    float4 sc = scp[(size_t)n * 64 + ch];
                    float sval = cs[r] + sc.x;
                    s[(size_t)n * 64 + ch] = sval;
                    v[(size_t)n * 192 + ch] = c0[r] + sc.y;
                    v[(size_t)n * 192 + 64 + ch] = c1[r] + sc.z;
                    v[(size_t)n * 192 + 128 + ch] = c2[r] + sc.w;
                    out[(size_t)origid[n] * (Ltot * 64) + layer * 64 + ch] = sval;
                }
            }
        }
    }
}

extern "C" void kernel_launch(void* const* d_in, const int* in_sizes, int n_in,
                              void* d_out, int out_size, void* d_ws, size_t ws_size,
                              hipStream_t stream) {
    const float* node_attrs = (const float*)d_in[0];
    const float* atom_pos   = (const float*)d_in[1];
    const float* shifts     = (const float*)d_in[2];
    const float* W_embed    = (const float*)d_in[3];
    const float* Wup_s      = (const float*)d_in[4];
    const float* Wup_v      = (const float*)d_in[5];
    const float* RW1        = (const float*)d_in[6];
    const float* RW2        = (const float*)d_in[7];
    const float* RW3        = (const float*)d_in[8];
    const float* Wout_s     = (const float*)d_in[9];
    const float* Wout_v     = (const float*)d_in[10];
    const float* Wsc_s      = (const float*)d_in[11];
    const float* Wsc_v      = (const float*)d_in[12];
    const float* P0         = (const float*)d_in[13];
    const float* P1         = (const float*)d_in[14];
    const float* Wprod_s    = (const float*)d_in[15];
    const float* Wprod_v    = (const float*)d_in[16];
    const int*   ei         = (const int*)d_in[17];

    const int N = in_sizes[0] / 10;
    const int E = in_sizes[17] / 2;
    const int L = in_sizes[4] / 4096;
    float* out = (float*)d_out;

    char* wsb = (char*)d_ws;
    size_t off = 0;
    auto alloci = [&](size_t n) {
        int* p = (int*)(wsb + off);
        off = (off + n * 4 + 255) / 256 * 256;
        return p;
    };
    auto allocf = [&](size_t n) {
        float* p = (float*)(wsb + off);
        off = (off + n * 4 + 255) / 256 * 256;
        return p;
    };
    auto alloch = [&](size_t n) {
        _Float16* p = (_Float16*)(wsb + off);
        off = (off + n * 2 + 255) / 256 * 256;
        return p;
    };
    int* species_o = alloci(N);
    int* species_s = alloci(N);
    int* zcount    = alloci(16);
    int* zcur      = alloci(16);
    int* perm_n    = alloci(N);
    int* inv_n     = alloci(N);
    int* origid    = alloci(N);
    int* deg       = alloci(N);
    int* rowptr    = alloci(N + 1);
    int* cursor    = alloci(N);
    int* perm      = alloci(E);
    int* snd_s     = alloci(E);
    float* s     = allocf((size_t)N * 64);
    float* v     = allocf((size_t)N * 192);
    float* agg0  = allocf((size_t)N * 64);
    float* agg1  = allocf((size_t)N * 192);
    float* geo   = allocf((size_t)E * 4);
    float* efT   = allocf((size_t)E * 8);
    float* pack  = allocf((size_t)N * 256);
    float* scp   = allocf((size_t)N * 256);
    _Float16* B1f   = alloch((size_t)L * 2048);
    _Float16* B2f   = alloch((size_t)L * 4096);
    _Float16* B3f   = alloch((size_t)L * 20480);
    _Float16* Bmats = alloch((size_t)L * 26 * 4096);

    // pick NCHUNK at runtime from ws_size (constant per session -> graph-safe)
    int NCHUNK = 16;
    int cap = 0;
    {
        const int cands[8] = {1, 2, 3, 4, 6, 8, 12, 16};
        for (int ci = 0; ci < 8; ci++) {
            int c = cands[ci];
            int thiscap = (c == 1) ? E : (E / c) * 5 / 4 + 256;
            size_t need = off + (size_t)thiscap * 512;
            if (need <= ws_size) { NCHUNK = c; cap = thiscap; break; }
        }
        if (cap == 0) { NCHUNK = 16; cap = (E / 16) * 5 / 4 + 256; }
    }
    float* msg = allocf((size_t)cap * 128);
    (void)n_in; (void)out_size;

    const int NT = (N + 63) / 64;
    const int NB = (N + 255) / 256;
    const int ET = (E + 63) / 64;
    const int EB = (E + 255) / 256;
    const int MT = (cap + 63) / 64;

    hipMemsetAsync(zcount, 0, 16 * sizeof(int), stream);
    hipMemsetAsync(deg, 0, (size_t)N * sizeof(int), stream);
    k_species<<<NB, 256, 0, stream>>>(node_attrs, species_o, zcount, N);
    k_zscan<<<1, 64, 0, stream>>>(zcount, zcur);
    k_zperm<<<NB, 256, 0, stream>>>(species_o, zcur, perm_n, inv_n, N);
    k_init<<<N, 64, 0, stream>>>(perm_n, species_o, W_embed, species_s, origid, s, v, N);
    k_hist<<<EB, 256, 0, stream>>>(ei, inv_n, deg, E);
    k_scan<<<1, 1024, 0, stream>>>(deg, rowptr, cursor, N);
    k_eperm<<<EB, 256, 0, stream>>>(ei, inv_n, cursor, perm, E);
    k_geom<<<ET, 64, 0, stream>>>(ei, perm, inv_n, atom_pos, shifts,
                                  (float4*)geo, efT, snd_s, E);
    k_wprep<<<52 * L, 64, 0, stream>>>(RW1, RW2, RW3, B1f, B2f, B3f);
    k_wprep_node<<<26 * L, 64, 0, stream>>>(Wup_s, Wup_v, Wout_s, Wout_v,
                                            Wprod_s, Wprod_v, Wsc_s, Wsc_v, Bmats);

    int nbound[17];
    for (int k = 0; k <= NCHUNK; k++) nbound[k] = (int)((long long)N * k / NCHUNK);

    for (int i = 0; i < L; i++) {
        const _Float16* Bl = Bmats + (size_t)i * 26 * 4096;
        k_nodeA<<<NT, 256, 0, stream>>>(s, v, species_s,
                                        Bl, Bl + 4096,
                                        Bl + 6 * 4096, Bl + 16 * 4096,
                                        Wsc_s + (size_t)i * 40960, Wsc_v + (size_t)i * 40960,
                                        (float4*)pack, (float4*)scp, N);
        for (int k = 0; k < NCHUNK; k++) {
            int na = nbound[k], nb = nbound[k + 1];
            k_msg<<<MT, 256, 0, stream>>>(rowptr, na, nb, efT, (const float4*)geo, snd_s,
                                          (const float4*)pack,
                                          B1f + (size_t)i * 2048, B2f + (size_t)i * 4096,
                                          B3f + (size_t)i * 20480, (float2*)msg, cap, E);
            int cnt = nb - na;
            k_agg<<<(cnt + 3) / 4, 256, 0, stream>>>((const float2*)msg, rowptr,
                                                     agg0, agg1, na, nb, cap);
        }
        k_nodeB<<<NT, 256, 0, stream>>>(agg0, agg1, species_s, origid,
                                        Bl + 2 * 4096, Bl + 3 * 4096,
                                        Bl + 4 * 4096, Bl + 5 * 4096,
                                        P0 + (size_t)i * 1920, P1 + (size_t)i * 1280,
                                        (const float4*)scp, s, v, out, N, i, L);
    }
}